// Round 1
// baseline (362.531 us; speedup 1.0000x reference)
//
#include <hip/hip_runtime.h>
#include <math.h>

#define HW4   12544                 // (224*224)/4
#define BATCH 128
#define NUM_CLASSES 1000
#define N4    (BATCH * HW4)         // 1,605,632 float4-groups
#define TPB   256
#define S     4                     // stages per pixel-block
#define PIXBLOCKS (N4 / (TPB * S))  // 1568 (exact)
#define CPB   (HW4 / TPB)           // 49 chunks per image (exact)
#define GRID  (PIXBLOCKS + BATCH)   // 1696

typedef float v4f __attribute__((ext_vector_type(4)));

// Direct global->LDS, 16B per lane, zero VGPR destination cost.
// LDS dest must be the wave-uniform base; HW adds lane*16.
__device__ __forceinline__ void gl_lds16(const v4f* g, v4f* l) {
    __builtin_amdgcn_global_load_lds(
        (const __attribute__((address_space(1))) void*)g,
        (__attribute__((address_space(3))) void*)l,
        16, 0, 0);
}

__launch_bounds__(TPB, 2)
__global__ void fused_loss_kernel(const v4f* __restrict__ objects,
                                  const v4f* __restrict__ locs,
                                  const v4f* __restrict__ gt,
                                  const float* __restrict__ scores,
                                  const int*   __restrict__ label,
                                  const float* __restrict__ obj_coor_p,
                                  const float* __restrict__ no_obj_confi_p,
                                  const float* __restrict__ img_class_weight_p,
                                  float* __restrict__ ws,
                                  float* __restrict__ out) {
    // 2 buffers x 8 streams x 256 v4f = exactly 64 KiB -> 2 blocks/CU
    __shared__ v4f lds[2][8][TPB];
    const int tid  = threadIdx.x;
    const int lane = tid & 63;
    const int wave = tid >> 6;

    if (blockIdx.x < BATCH) {
        // ---------------- class loss: one block per batch row ----------------
        const int b = blockIdx.x;
        const float* row = scores + b * NUM_CLASSES;
        float* red = (float*)lds;            // [0..3] partials, [4] bcast

        float mx = -INFINITY;
        for (int i = tid; i < NUM_CLASSES; i += TPB)
            mx = fmaxf(mx, row[i]);
#pragma unroll
        for (int off = 32; off > 0; off >>= 1)
            mx = fmaxf(mx, __shfl_down(mx, off, 64));
        if (lane == 0) red[wave] = mx;
        __syncthreads();
        if (tid == 0)
            red[4] = fmaxf(fmaxf(red[0], red[1]), fmaxf(red[2], red[3]));
        __syncthreads();
        mx = red[4];

        float se = 0.0f;
        for (int i = tid; i < NUM_CLASSES; i += TPB)
            se += __expf(row[i] - mx);
#pragma unroll
        for (int off = 32; off > 0; off >>= 1)
            se += __shfl_down(se, off, 64);
        __syncthreads();
        if (lane == 0) red[wave] = se;
        __syncthreads();
        if (tid == 0) {
            float lse = mx + logf(red[0] + red[1] + red[2] + red[3]);
            atomicAdd(&ws[1], -(row[label[b]] - lse));
        }
    } else {
        // ---------------- pixel loss: software-pipelined LDS streaming -------
        float coorW = *obj_coor_p;
        float noW   = *no_obj_confi_p;
        // Materialize coefficient loads NOW and drain them, so the counted
        // vmcnt() bookkeeping below is exact (10 VMEM ops per stage batch).
        asm volatile("" : "+v"(coorW), "+v"(noW));
        asm volatile("s_waitcnt vmcnt(0)" ::: "memory");

        const unsigned c0 = (blockIdx.x - BATCH) * S;
        v4f o_r[2], m_r[2];

        // Issue one stage's batch: 2 register loads (objects, gt0) + 8
        // global_load_lds (gt rows 1..4, locs rows 0..3) = 10 VMEM ops.
        // Each wave writes ONLY its own 64-lane slice of every stream,
        // and later reads only that slice -> no barriers needed in the loop.
        auto issue = [&](int s, int buf) {
            const unsigned c  = c0 + (unsigned)s;
            const unsigned b  = c / CPB;                    // image index
            const unsigned hw = (c - b * CPB) * TPB + tid;  // float4 offset in image
            const v4f* gtp = gt   + (size_t)b * (5 * HW4) + hw;
            const v4f* lcp = locs + (size_t)b * (4 * HW4) + hw;
            o_r[buf] = objects[(size_t)b * HW4 + hw];
            m_r[buf] = gtp[0];
            v4f* dst0 = &lds[buf][0][wave << 6];   // wave-uniform bases
            gl_lds16(gtp + 1 * HW4, &lds[buf][0][wave << 6]);
            gl_lds16(gtp + 2 * HW4, &lds[buf][1][wave << 6]);
            gl_lds16(gtp + 3 * HW4, &lds[buf][2][wave << 6]);
            gl_lds16(gtp + 4 * HW4, &lds[buf][3][wave << 6]);
            gl_lds16(lcp + 0 * HW4, &lds[buf][4][wave << 6]);
            gl_lds16(lcp + 1 * HW4, &lds[buf][5][wave << 6]);
            gl_lds16(lcp + 2 * HW4, &lds[buf][6][wave << 6]);
            gl_lds16(lcp + 3 * HW4, &lds[buf][7][wave << 6]);
            (void)dst0;
        };

        issue(0, 0);
        float acc = 0.0f;
#pragma unroll
        for (int s = 0; s < S; ++s) {
            const int buf = s & 1;
            if (s + 1 < S) {
                issue(s + 1, buf ^ 1);
                // batch s+1 (10 ops) stays in flight; waiting to <=10
                // outstanding means batch s has fully landed in LDS/regs.
                asm volatile("s_waitcnt vmcnt(10)" ::: "memory");
            } else {
                asm volatile("s_waitcnt vmcnt(0)" ::: "memory");
            }
            v4f sq = {0.f, 0.f, 0.f, 0.f};
#pragma unroll
            for (int j = 0; j < 4; ++j) {
                v4f g = lds[buf][j][tid];
                v4f l = lds[buf][4 + j][tid];
                v4f d = l - g;
                sq += d * d;
            }
            const v4f o = o_r[buf], m = m_r[buf];
#pragma unroll
            for (int j = 0; j < 4; ++j) {
                const float p  = o[j];
                const float mm = m[j];               // exactly 0.0f or 1.0f
                const float lognop = fmaxf(__logf(1.0f - p), -100.0f);
                const float logp   = fmaxf(__logf(p),        -100.0f);
                const float a  = -noW * lognop;              // m==0 contribution
                const float bb = fmaf(coorW, sq[j], -logp);  // m==1 contribution
                acc += fmaf(mm, bb - a, a);                  // a + m*(b-a)
            }
        }

        // ---- wave reduce, then cross-wave via LDS (now safe to reuse) ----
#pragma unroll
        for (int off = 32; off > 0; off >>= 1)
            acc += __shfl_down(acc, off, 64);
        __syncthreads();                 // all waves done streaming before reuse
        float* red = (float*)lds;
        if (lane == 0) red[wave] = acc;
        __syncthreads();
        if (tid == 0)
            atomicAdd(&ws[0], red[0] + red[1] + red[2] + red[3]);
    }

    // ---------------- last-block finalize (replaces finalize_kernel) --------
    if (tid == 0) {
        __threadfence();                                  // publish our adds
        unsigned done = atomicAdd((unsigned int*)&ws[2], 1u);
        if (done == (unsigned)(GRID - 1)) {
            __threadfence();
            const float pix = atomicAdd(&ws[0], 0.0f);    // device-scope read
            const float cls = atomicAdd(&ws[1], 0.0f);
            out[0] = img_class_weight_p[0] * (cls / (float)BATCH)
                   + pix / (float)BATCH;
        }
    }
}

extern "C" void kernel_launch(void* const* d_in, const int* in_sizes, int n_in,
                              void* d_out, int out_size, void* d_ws, size_t ws_size,
                              hipStream_t stream) {
    const float* objects = (const float*)d_in[0];   // (B,H,W)
    const float* scores  = (const float*)d_in[1];   // (B,1000)
    const float* locs    = (const float*)d_in[2];   // (B,4,H,W)
    const int*   label   = (const int*)d_in[3];     // (B,)
    const float* gt      = (const float*)d_in[4];   // (B,5,H,W)
    const float* obj_coor         = (const float*)d_in[5];
    const float* no_obj_confi     = (const float*)d_in[6];
    const float* img_class_weight = (const float*)d_in[7];

    float* ws  = (float*)d_ws;                      // [0]=pix, [1]=cls, [2]=counter
    float* out = (float*)d_out;

    hipMemsetAsync(ws, 0, 3 * sizeof(float), stream);

    fused_loss_kernel<<<GRID, TPB, 0, stream>>>(
        (const v4f*)objects, (const v4f*)locs, (const v4f*)gt,
        scores, label, obj_coor, no_obj_confi, img_class_weight, ws, out);
}

// Round 2
// 324.318 us; speedup vs baseline: 1.1178x; 1.1178x over previous
//
#include <hip/hip_runtime.h>
#include <math.h>

#define HW4   12544                 // (224*224)/4
#define BATCH 128
#define NUM_CLASSES 1000
#define N4    (BATCH * HW4)         // 1,605,632 float4-groups
#define TPB   256
#define S     8                     // pipeline depth: stages per thread
#define PIXBLOCKS (N4 / (TPB * S))  // 784 (exact)
#define STRIDE (PIXBLOCKS * TPB)    // 200,704 float4-groups per stage
#define GRID  (PIXBLOCKS + BATCH)   // 912

typedef float v4f __attribute__((ext_vector_type(4)));

struct Batch { v4f o, m, gc[4], lc[4]; };   // 10 v4f = 40 VGPRs

__launch_bounds__(TPB, 4)   // cap 128 VGPRs -> 4 waves/SIMD, 16 waves/CU
__global__ void fused_loss_kernel(const v4f* __restrict__ objects,
                                  const v4f* __restrict__ locs,
                                  const v4f* __restrict__ gt,
                                  const float* __restrict__ scores,
                                  const int*   __restrict__ label,
                                  const float* __restrict__ obj_coor_p,
                                  const float* __restrict__ no_obj_confi_p,
                                  const float* __restrict__ img_class_weight_p,
                                  float* __restrict__ ws,
                                  float* __restrict__ out) {
    __shared__ float red[8];
    const int tid  = threadIdx.x;
    const int lane = tid & 63;
    const int wave = tid >> 6;

    if (blockIdx.x < BATCH) {
        // ---------------- class loss: one block per batch row ----------------
        const int b = blockIdx.x;
        const float* row = scores + b * NUM_CLASSES;

        float mx = -INFINITY;
        for (int i = tid; i < NUM_CLASSES; i += TPB)
            mx = fmaxf(mx, row[i]);
#pragma unroll
        for (int off = 32; off > 0; off >>= 1)
            mx = fmaxf(mx, __shfl_down(mx, off, 64));
        if (lane == 0) red[wave] = mx;
        __syncthreads();
        if (tid == 0)
            red[4] = fmaxf(fmaxf(red[0], red[1]), fmaxf(red[2], red[3]));
        __syncthreads();
        mx = red[4];

        float se = 0.0f;
        for (int i = tid; i < NUM_CLASSES; i += TPB)
            se += __expf(row[i] - mx);
#pragma unroll
        for (int off = 32; off > 0; off >>= 1)
            se += __shfl_down(se, off, 64);
        __syncthreads();
        if (lane == 0) red[wave] = se;
        __syncthreads();
        if (tid == 0) {
            float lse = mx + logf(red[0] + red[1] + red[2] + red[3]);
            atomicAdd(&ws[1], -(row[label[b]] - lse));
        }
    } else {
        // -------- pixel loss: register double-buffered pipeline, depth S -----
        const float coorW = *obj_coor_p;
        const float noW   = *no_obj_confi_p;
        const unsigned base = (unsigned)(blockIdx.x - BATCH) * TPB + tid;

        Batch bat[2];            // static indices only (fully unrolled below)
        float acc = 0.0f;

        auto issue = [&](int s, Batch& B) {
            const unsigned g   = base + (unsigned)s * (unsigned)STRIDE;
            const unsigned b   = g / HW4;                 // magic-mul
            const unsigned gtb = g + 4u * HW4 * b;        // gt row-0 index
            const unsigned lcb = g + 3u * HW4 * b;        // locs row-0 index
            B.o = objects[g];                             // objects is linear in g
            B.m = gt[gtb];
#pragma unroll
            for (int c = 0; c < 4; ++c) {
                B.gc[c] = gt[gtb + (unsigned)((1 + c) * HW4)];
                B.lc[c] = locs[lcb + (unsigned)(c * HW4)];
            }
        };

        auto computeB = [&](const Batch& B) {
            v4f sq = {0.f, 0.f, 0.f, 0.f};
#pragma unroll
            for (int c = 0; c < 4; ++c) {
                v4f d = B.lc[c] - B.gc[c];
                sq += d * d;
            }
#pragma unroll
            for (int j = 0; j < 4; ++j) {
                const float p  = B.o[j];
                const float mm = B.m[j];                  // exactly 0.0f or 1.0f
                const float lognop = fmaxf(__logf(1.0f - p), -100.0f);
                const float logp   = fmaxf(__logf(p),        -100.0f);
                const float a  = -noW * lognop;               // m==0 contribution
                const float bb = fmaf(coorW, sq[j], -logp);   // m==1 contribution
                acc += fmaf(mm, bb - a, a);                   // a + m*(b-a)
            }
        };

        // Software pipeline: batch s+1's 10 loads are issued BEFORE batch s is
        // consumed. vmcnt completes in-order, so the compiler's auto-waitcnt
        // before the first use of batch s is a counted wait (~vmcnt(10)) --
        // the next batch stays in flight across the entire compute phase.
        issue(0, bat[0]);
#pragma unroll
        for (int s = 0; s < S; ++s) {
            if (s + 1 < S) issue(s + 1, bat[(s + 1) & 1]);
            computeB(bat[s & 1]);
        }

        // ---- wave reduce, then cross-wave via LDS ----
#pragma unroll
        for (int off = 32; off > 0; off >>= 1)
            acc += __shfl_down(acc, off, 64);
        if (lane == 0) red[wave] = acc;
        __syncthreads();
        if (tid == 0)
            atomicAdd(&ws[0], red[0] + red[1] + red[2] + red[3]);
    }

    // ---------------- last-block finalize ----------------
    if (tid == 0) {
        __threadfence();                                  // publish our adds
        unsigned done = atomicAdd((unsigned int*)&ws[2], 1u);
        if (done == (unsigned)(GRID - 1)) {
            __threadfence();
            const float pix = atomicAdd(&ws[0], 0.0f);    // device-scope read
            const float cls = atomicAdd(&ws[1], 0.0f);
            out[0] = img_class_weight_p[0] * (cls / (float)BATCH)
                   + pix / (float)BATCH;
        }
    }
}

extern "C" void kernel_launch(void* const* d_in, const int* in_sizes, int n_in,
                              void* d_out, int out_size, void* d_ws, size_t ws_size,
                              hipStream_t stream) {
    const float* objects = (const float*)d_in[0];   // (B,H,W)
    const float* scores  = (const float*)d_in[1];   // (B,1000)
    const float* locs    = (const float*)d_in[2];   // (B,4,H,W)
    const int*   label   = (const int*)d_in[3];     // (B,)
    const float* gt      = (const float*)d_in[4];   // (B,5,H,W)
    const float* obj_coor         = (const float*)d_in[5];
    const float* no_obj_confi     = (const float*)d_in[6];
    const float* img_class_weight = (const float*)d_in[7];

    float* ws  = (float*)d_ws;                      // [0]=pix, [1]=cls, [2]=counter
    float* out = (float*)d_out;

    hipMemsetAsync(ws, 0, 3 * sizeof(float), stream);

    fused_loss_kernel<<<GRID, TPB, 0, stream>>>(
        (const v4f*)objects, (const v4f*)locs, (const v4f*)gt,
        scores, label, obj_coor, no_obj_confi, img_class_weight, ws, out);
}